// Round 3
// baseline (3241.644 us; speedup 1.0000x reference)
//
#include <hip/hip_runtime.h>
#include <math.h>

typedef unsigned short u16;
typedef short s16x8 __attribute__((ext_vector_type(8)));
typedef float f32x4 __attribute__((ext_vector_type(4)));

#define HW 3600
#define WID 60
#define SIMS 3616      // padded K/N stride for attention (113*32)
#define AROWS 3712     // attn rows padded to 29*128
#define SP 4216        // 62*68 padded spatial
#define PCIN 2048

__device__ __forceinline__ u16 f2bf(float f){
  unsigned u = __float_as_uint(f);
  unsigned r = (u + 0x7fffu + ((u>>16)&1u)) >> 16;
  return (u16)r;
}
__device__ __forceinline__ float bf2f(u16 b){ return __uint_as_float(((unsigned)b)<<16); }

__device__ __forceinline__ void gl2lds16(const void* g, void* l){
  __builtin_amdgcn_global_load_lds((const __attribute__((address_space(1))) unsigned*)g,
                                   (__attribute__((address_space(3))) unsigned*)l, 16, 0, 0);
}

__device__ __forceinline__ float4 ldg4(const float* __restrict__ p){
  return *reinterpret_cast<const float4*>(p);
}

// ---------------- BN folding ----------------
__global__ void bn_prep(const float* __restrict__ w1, const float* __restrict__ b1,
                        const float* __restrict__ m1, const float* __restrict__ v1,
                        const float* __restrict__ w2, const float* __restrict__ b2,
                        const float* __restrict__ m2, const float* __restrict__ v2,
                        float* __restrict__ sc1, float* __restrict__ sh1,
                        float* __restrict__ sc2, float* __restrict__ sh2){
  int i = threadIdx.x;
  if(i < 512){
    float s1 = w1[i] / sqrtf(v1[i] + 1e-5f);
    sc1[i] = s1; sh1[i] = b1[i] - m1[i]*s1;
    float s2 = w2[i] / sqrtf(v2[i] + 1e-5f);
    sc2[i] = s2; sh2[i] = b2[i] - m2[i]*s2;
  }
}

// ---------------- pack x -> xpadT[plane][b][sp][ci] bf16 split ----------------
__global__ __launch_bounds__(256) void pack_x(const float* __restrict__ x, u16* __restrict__ xpadT){
  __shared__ float tile[64][65];
  const int b = blockIdx.z, sp0 = blockIdx.x*64, ci0 = blockIdx.y*64;
  const int t = threadIdx.x, tc = t & 63, tr = t >> 6;
  const float* xb = x + ((size_t)b*PCIN + ci0)*HW;
  #pragma unroll
  for(int l=0;l<16;l++){
    int ci = tr + l*4;
    int sp = sp0 + tc;
    float v = 0.f;
    if(sp < SP){
      int j = sp / 68, c = sp - j*68;
      int jj = j-1, cc = c-1;
      if((unsigned)jj < 60u && (unsigned)cc < 60u) v = xb[(size_t)ci*HW + jj*60 + cc];
    }
    tile[ci][tc] = v;
  }
  __syncthreads();
  const size_t PL = (size_t)4*SP*PCIN;
  u16* outb = xpadT + (size_t)b*SP*PCIN;
  #pragma unroll
  for(int l=0;l<16;l++){
    int spr = tr + l*4;
    int sp = sp0 + spr;
    if(sp < SP){
      float v = tile[tc][spr];
      u16 hh = f2bf(v);
      u16 ll = f2bf(v - bf2f(hh));
      size_t o = (size_t)sp*PCIN + ci0 + tc;
      outb[o] = hh;
      outb[o + PL] = ll;
    }
  }
}

// ---------------- pack w5a -> [rs][512][6144] (wh | wl | wh) ----------------
__global__ __launch_bounds__(256) void pack_w5a(const float* __restrict__ w, u16* __restrict__ out){
  const int ci = blockIdx.x*256 + threadIdx.x;   // 0..2047
  const int m  = blockIdx.y;
  const int rs = blockIdx.z;
  float v = w[((size_t)m*PCIN + ci)*9 + rs];
  u16 hh = f2bf(v);
  u16 ll = f2bf(v - bf2f(hh));
  size_t base = ((size_t)rs*512 + m)*6144;
  out[base + ci]        = hh;
  out[base + 2048 + ci] = ll;
  out[base + 4096 + ci] = hh;
}

// ---------------- pack w51 -> [rs][512][512] bf16 ----------------
__global__ __launch_bounds__(256) void pack_w51(const float* __restrict__ w, u16* __restrict__ out){
  const int ci = blockIdx.x*256 + threadIdx.x;   // 0..511
  const int m  = blockIdx.y;
  const int rs = blockIdx.z;
  float v = w[((size_t)m*512 + ci)*9 + rs];
  out[((size_t)rs*512 + m)*512 + ci] = f2bf(v);
}

// ---------------- MFMA GEMM (128x128 tile, BK=32, 8 waves, 3-buf async) ----------------
// MODE 0: conv5a  A=W5a[rs][512][6144], B=xpadT (2 planes), out f1 f32 (BN1+ReLU)
// MODE 1: conv51  A=W51[rs][512][512],  B=sapadT,           out sc bf16 (BN2+ReLU)
// MODE 2: PV      A=v bf16 [512][SIMS], B=attn bf16,        out sapadT (gamma*acc+f1)
template<int MODE>
__global__ __launch_bounds__(512) void mfma_gemm(
    const u16* __restrict__ A, const u16* __restrict__ B,
    const float* __restrict__ scale, const float* __restrict__ shift,
    const float* __restrict__ f1, const float* __restrict__ gamma,
    float* __restrict__ outF, u16* __restrict__ outH)
{
  constexpr int CIC = (MODE==0)? 2048 : 512;
  constexpr int KRS = (MODE==0)? 6144 : 512;
  constexpr int KPR = KRS/32;
  constexpr int NSTEP = (MODE==2)? (SIMS/32) : (9*KPR);
  constexpr int NTA = (MODE==2)? 116 : 120;   // n-tiles * batches
  constexpr int NB  = (MODE==2)? 29  : 30;

  __shared__ __align__(16) u16 lds[3*8192];   // 3 bufs x (A 8KB + B 8KB)

  const int t  = threadIdx.x;

  // bijective XCD-chunked, m-major decomposition (grid % 8 == 0)
  const int wg = blockIdx.x;
  const int chunk = (4*NTA) >> 3;
  const int wgid = (wg & 7) * chunk + (wg >> 3);
  const int mt = wgid / NTA;
  const int nt = wgid - mt*NTA;
  const int m0 = mt << 7;
  const int b  = nt / NB;
  const int nb = nt - b*NB;

  // staging roles: thread t stages 16B at LDS offset t*16 of each 8KB tile
  const int srow = t & 127;
  const int skc  = t >> 7;   // 0..3

  const u16* Abase;
  if constexpr(MODE==2) Abase = A + (size_t)b*512*SIMS + (size_t)(m0+srow)*SIMS + skc*8;
  else                  Abase = A + (size_t)(m0+srow)*KRS + skc*8;

  const u16* Bbase;
  if constexpr(MODE==2){
    Bbase = B + (size_t)b*AROWS*SIMS + (size_t)(nb*128 + srow)*SIMS + skc*8;
  } else {
    int seg = srow >> 6, wl = srow & 63;
    int spb = (nb*2 + seg)*68 + wl;
    Bbase = B + (size_t)b*SP*CIC + (size_t)spb*CIC + skc*8;
  }
  const size_t PL = (size_t)4*SP*PCIN;

  f32x4 acc[4][2];
  #pragma unroll
  for(int i=0;i<4;i++)
    #pragma unroll
    for(int j=0;j<2;j++) acc[i][j] = (f32x4){0.f,0.f,0.f,0.f};

  const int lane = t & 63;
  const int wv = t >> 6;               // 0..7
  const int wm = (wv >> 2) << 6;       // {0,64}
  const int wn = (wv & 3) << 5;        // {0,32,64,96}
  const int fr = lane & 15, fq = lane >> 4;
  const char* ldsc = (const char*)lds;
  const int aoff = fq*2048 + (wm+fr)*16;          // bytes in A region [0,8192)
  const int boff = 8192 + fq*2048 + (wn+fr)*16;   // bytes in B region

  auto stage = [&](int st, int q){
    int rs = 0, k0;
    if constexpr(MODE==2){ k0 = st << 5; }
    else { rs = st / KPR; k0 = (st - rs*KPR) << 5; }
    const u16* ga;
    if constexpr(MODE==2) ga = Abase + k0;
    else                  ga = Abase + (size_t)rs*512*KRS + k0;
    gl2lds16(ga, &lds[(size_t)q*8192 + t*8]);
    const u16* gb;
    if constexpr(MODE==2){ gb = Bbase + k0; }
    else {
      int r = rs/3, s = rs - r*3;
      int plane = (MODE==0)? (k0 >> 12) : 0;
      int ci0 = k0 & (CIC-1);
      gb = Bbase + (size_t)plane*PL + (size_t)(r*68 + s)*CIC + ci0;
    }
    gl2lds16(gb, &lds[(size_t)q*8192 + 4096 + t*8]);
  };

  auto compute = [&](int q){
    const char* base = ldsc + q*16384;
    s16x8 af[4], bg[2];
    #pragma unroll
    for(int i=0;i<4;i++) af[i] = *(const s16x8*)(base + aoff + i*256);
    #pragma unroll
    for(int j=0;j<2;j++) bg[j] = *(const s16x8*)(base + boff + j*256);
    __builtin_amdgcn_s_setprio(1);
    #pragma unroll
    for(int i=0;i<4;i++)
      #pragma unroll
      for(int j=0;j<2;j++)
        acc[i][j] = __builtin_amdgcn_mfma_f32_16x16x32_bf16(af[i], bg[j], acc[i][j], 0,0,0);
    __builtin_amdgcn_s_setprio(0);
  };

  // prologue: 2 tiles in flight
  stage(0, 0);
  stage(1, 1);
  int cur = 0;
  for(int st = 0; st < NSTEP-2; ++st){
    int q2 = cur + 2; if(q2 >= 3) q2 -= 3;
    stage(st+2, q2);
    asm volatile("s_waitcnt vmcnt(4)" ::: "memory");
    __builtin_amdgcn_s_barrier();
    asm volatile("" ::: "memory");
    compute(cur);
    asm volatile("" ::: "memory");
    __builtin_amdgcn_s_barrier();
    asm volatile("" ::: "memory");
    cur = (cur+1 == 3)? 0 : cur+1;
  }
  asm volatile("s_waitcnt vmcnt(2)" ::: "memory");
  __builtin_amdgcn_s_barrier();
  asm volatile("" ::: "memory");
  compute(cur);
  cur = (cur+1 == 3)? 0 : cur+1;
  asm volatile("s_waitcnt vmcnt(0)" ::: "memory");
  __builtin_amdgcn_s_barrier();
  asm volatile("" ::: "memory");
  compute(cur);

  if constexpr(MODE==0 || MODE==1){
    #pragma unroll
    for(int i=0;i<4;i++){
      #pragma unroll
      for(int q=0;q<4;q++){
        int m = m0 + wm + i*16 + fq*4 + q;
        float scl = scale[m], shf = shift[m];
        #pragma unroll
        for(int j=0;j<2;j++){
          int np = nb*128 + wn + j*16 + fr;
          int h = np>>6, w = np&63;
          if(w < 60){
            float v = fmaxf(fmaf(acc[i][j][q], scl, shf), 0.f);
            size_t o = ((size_t)b*512 + m)*HW + h*60 + w;
            if constexpr(MODE==0) outF[o] = v;
            else                  outH[o] = f2bf(v);
          }
        }
      }
    }
  } else {
    float g = gamma[0];
    #pragma unroll
    for(int j=0;j<2;j++){
      int ip = nb*128 + wn + j*16 + fr;
      if(ip < HW){
        int h = ip/60, w = ip - h*60;
        size_t spo = (size_t)b*SP*512 + (size_t)((h+1)*68 + (w+1))*512;
        #pragma unroll
        for(int i=0;i<4;i++){
          #pragma unroll
          for(int q=0;q<4;q++){
            int m = m0 + wm + i*16 + fq*4 + q;
            float v = fmaf(g, acc[i][j][q], f1[((size_t)b*512 + m)*HW + ip]);
            outH[spo + m] = f2bf(v);
          }
        }
      }
    }
  }
}

// ---------------- 1x1 conv GEMM (f32 compute) ----------------
template<bool INBF, bool GM, bool OUTBF>
__global__ __launch_bounds__(256) void gemm1x1(const void* __restrict__ inv,
    const float* __restrict__ w, const float* __restrict__ bias,
    float* __restrict__ outF, u16* __restrict__ outH, int M, int K, int OS)
{
  const int b  = blockIdx.z;
  const int m0 = blockIdx.x * 64;
  const int n0 = blockIdx.y * 64;
  const int t  = threadIdx.x;
  const int tm = t >> 4, tn = t & 15;

  __shared__ __align__(16) float As[16][64];
  __shared__ __align__(16) float Bs[16][64];

  float acc[4][4] = {};

  const int arow = t >> 2, acol = (t & 3) << 2;
  const int bkk  = t & 15, bnl  = (t >> 4) << 2;
  const bool bvalid = (n0 + bnl) < HW;

  for(int k0 = 0; k0 < K; k0 += 16){
    float4 av = make_float4(0.f,0.f,0.f,0.f);
    if(!GM || (m0 + arow) < M)
      av = ldg4(&w[(size_t)(m0 + arow)*K + k0 + acol]);
    As[acol+0][arow] = av.x;
    As[acol+1][arow] = av.y;
    As[acol+2][arow] = av.z;
    As[acol+3][arow] = av.w;

    float4 bv = make_float4(0.f,0.f,0.f,0.f);
    if(bvalid){
      if constexpr(INBF){
        const u16* inb = (const u16*)inv + (size_t)b*K*HW;
        const u16* p = &inb[(size_t)(k0 + bkk)*HW + n0 + bnl];
        bv.x = bf2f(p[0]); bv.y = bf2f(p[1]); bv.z = bf2f(p[2]); bv.w = bf2f(p[3]);
      } else {
        const float* inb = (const float*)inv + (size_t)b*K*HW;
        bv = ldg4(&inb[(size_t)(k0 + bkk)*HW + n0 + bnl]);
      }
    }
    *reinterpret_cast<float4*>(&Bs[bkk][bnl]) = bv;

    __syncthreads();
    #pragma unroll
    for(int kk=0;kk<16;kk++){
      float4 a  = *reinterpret_cast<const float4*>(&As[kk][tm<<2]);
      float4 bb = *reinterpret_cast<const float4*>(&Bs[kk][tn<<2]);
      float ar[4] = {a.x,a.y,a.z,a.w};
      float br[4] = {bb.x,bb.y,bb.z,bb.w};
      #pragma unroll
      for(int ii=0;ii<4;ii++)
        #pragma unroll
        for(int jj=0;jj<4;jj++)
          acc[ii][jj] = fmaf(ar[ii], br[jj], acc[ii][jj]);
    }
    __syncthreads();
  }

  int n = n0 + (tn<<2);
  if(n < OS){
    #pragma unroll
    for(int ii=0;ii<4;ii++){
      int m = m0 + (tm<<2) + ii;
      if(!GM || m < M){
        float bi = bias[m];
        #pragma unroll
        for(int jj=0;jj<4;jj++){
          int nn = n + jj;
          float val = (nn < HW) ? (acc[ii][jj] + bi) : 0.f;
          if constexpr(OUTBF) outH[((size_t)b*M + m)*OS + nn] = f2bf(val);
          else                outF[((size_t)b*M + m)*OS + nn] = val;
        }
      }
    }
  }
}

// ---------------- energy + depth penalty (f32) ----------------
__global__ __launch_bounds__(256) void energy_sim(
    const float* __restrict__ q, const float* __restrict__ kptr,
    const float* __restrict__ dep, const float* __restrict__ lamb1,
    float* __restrict__ sim)
{
  const int i0 = blockIdx.y * 64;
  const int j0 = blockIdx.x * 64;
  const int t  = threadIdx.x;
  const int tm = t >> 4, tn = t & 15;

  __shared__ __align__(16) float Qs[64][64];
  __shared__ __align__(16) float Ks[64][64];

  {
    const int cc = t >> 4;
    const int il = (t & 15) << 2;
    #pragma unroll
    for(int it=0; it<4; it++){
      int c = cc + it*16;
      float4 qv = make_float4(0.f,0.f,0.f,0.f);
      float4 kv = make_float4(0.f,0.f,0.f,0.f);
      if(i0 + il < HW) qv = ldg4(&q[(size_t)c*HW + i0 + il]);
      if(j0 + il < HW) kv = ldg4(&kptr[(size_t)c*HW + j0 + il]);
      *reinterpret_cast<float4*>(&Qs[c][il]) = qv;
      *reinterpret_cast<float4*>(&Ks[c][il]) = kv;
    }
  }
  __syncthreads();

  float acc[4][4] = {};
  #pragma unroll 4
  for(int c=0;c<64;c++){
    float4 a  = *reinterpret_cast<const float4*>(&Qs[c][tm<<2]);
    float4 bv = *reinterpret_cast<const float4*>(&Ks[c][tn<<2]);
    float ar[4] = {a.x,a.y,a.z,a.w};
    float br[4] = {bv.x,bv.y,bv.z,bv.w};
    #pragma unroll
    for(int ii=0;ii<4;ii++)
      #pragma unroll
      for(int jj=0;jj<4;jj++)
        acc[ii][jj] = fmaf(ar[ii], br[jj], acc[ii][jj]);
  }

  float lam = lamb1[0];
  float di[4], dj[4];
  #pragma unroll
  for(int ii=0;ii<4;ii++){ int i = i0+(tm<<2)+ii; di[ii] = (i<HW)? dep[i] : 0.f; }
  #pragma unroll
  for(int jj=0;jj<4;jj++){ int j = j0+(tn<<2)+jj; dj[jj] = (j<HW)? dep[j] : 0.f; }

  int j = j0 + (tn<<2);
  if(j < HW){
    #pragma unroll
    for(int ii=0;ii<4;ii++){
      int i = i0 + (tm<<2) + ii;
      if(i < HW){
        float4 o;
        float d0 = di[ii]-dj[0]; o.x = acc[ii][0] - lam*d0*d0;
        float d1 = di[ii]-dj[1]; o.y = acc[ii][1] - lam*d1*d1;
        float d2 = di[ii]-dj[2]; o.z = acc[ii][2] - lam*d2*d2;
        float d3 = di[ii]-dj[3]; o.w = acc[ii][3] - lam*d3*d3;
        *reinterpret_cast<float4*>(&sim[(size_t)i*SIMS + j]) = o;
      }
    }
  }
}

// ---------------- row softmax -> bf16 attn (2-pass, online max/sum) ----------------
__global__ __launch_bounds__(256) void softmax_attn(const float* __restrict__ sim,
                                                    u16* __restrict__ attn){
  __shared__ float redM[4], redS[4];
  const int row = blockIdx.x;
  const float* p = sim + (size_t)row*SIMS;
  u16*   a = attn + (size_t)row*SIMS;
  const int wid = threadIdx.x >> 6, lane = threadIdx.x & 63;

  float m = -3.4e38f, s = 0.f;
  for(int j=threadIdx.x; j<HW; j+=256){
    float v = p[j];
    float mo = m;
    m = fmaxf(m, v);
    s = s*__expf(mo - m) + __expf(v - m);
  }
  #pragma unroll
  for(int o=32;o>0;o>>=1){
    float m2 = __shfl_xor(m, o, 64);
    float s2 = __shfl_xor(s, o, 64);
    float mn = fmaxf(m, m2);
    s = s*__expf(m - mn) + s2*__expf(m2 - mn);
    m = mn;
  }
  if(lane==0){ redM[wid] = m; redS[wid] = s; }
  __syncthreads();
  float M = fmaxf(fmaxf(redM[0],redM[1]), fmaxf(redM[2],redM[3]));
  float S = redS[0]*__expf(redM[0]-M) + redS[1]*__expf(redM[1]-M)
          + redS[2]*__expf(redM[2]-M) + redS[3]*__expf(redM[3]-M);
  float inv = 1.0f / S;
  for(int j=threadIdx.x; j<HW; j+=256) a[j] = f2bf(__expf(p[j]-M) * inv);
  if(threadIdx.x < SIMS-HW) a[HW + threadIdx.x] = 0;
}

extern "C" void kernel_launch(void* const* d_in, const int* in_sizes, int n_in,
                              void* d_out, int out_size, void* d_ws, size_t ws_size,
                              hipStream_t stream)
{
  const float* x    = (const float*)d_in[0];
  const float* dep  = (const float*)d_in[1];
  const float* w5a  = (const float*)d_in[2];
  const float* bn1w = (const float*)d_in[3];
  const float* bn1b = (const float*)d_in[4];
  const float* bn1m = (const float*)d_in[5];
  const float* bn1v = (const float*)d_in[6];
  const float* wq   = (const float*)d_in[7];
  const float* bq   = (const float*)d_in[8];
  const float* wk   = (const float*)d_in[9];
  const float* bk   = (const float*)d_in[10];
  const float* wv   = (const float*)d_in[11];
  const float* bv   = (const float*)d_in[12];
  const float* gamma= (const float*)d_in[13];
  const float* lamb1= (const float*)d_in[14];
  const float* w51  = (const float*)d_in[15];
  const float* bn2w = (const float*)d_in[16];
  const float* bn2b = (const float*)d_in[17];
  const float* bn2m = (const float*)d_in[18];
  const float* bn2v = (const float*)d_in[19];
  const float* w6   = (const float*)d_in[20];
  const float* b6   = (const float*)d_in[21];
  float* out = (float*)d_out;

  char* cur = (char*)d_ws;
  auto alloc = [&](size_t bytes)->char*{ char* p = cur; cur += (bytes + 255) & ~(size_t)255; return p; };

  float* sc1 = (float*)alloc(512*4);
  float* sh1 = (float*)alloc(512*4);
  float* sc2 = (float*)alloc(512*4);
  float* sh2 = (float*)alloc(512*4);
  u16* xpadT = (u16*)alloc((size_t)2*4*SP*PCIN*2);
  u16* W5ab  = (u16*)alloc((size_t)9*512*6144*2);
  u16* W51b  = (u16*)alloc((size_t)9*512*512*2);
  float* f1  = (float*)alloc((size_t)4*512*HW*4);
  float* qb  = (float*)alloc((size_t)4*64*HW*4);
  float* kb  = (float*)alloc((size_t)4*64*HW*4);
  u16* vb    = (u16*)alloc((size_t)4*512*SIMS*2);
  float* sim = (float*)alloc((size_t)HW*SIMS*4);
  u16* attn  = (u16*)alloc((size_t)4*AROWS*SIMS*2);
  u16* sapadT= (u16*)alloc((size_t)4*SP*512*2);
  u16* scb   = (u16*)alloc((size_t)4*512*HW*2);

  bn_prep<<<1, 512, 0, stream>>>(bn1w,bn1b,bn1m,bn1v, bn2w,bn2b,bn2m,bn2v,
                                 sc1,sh1,sc2,sh2);

  hipMemsetAsync(sapadT, 0, (size_t)4*SP*512*2, stream);

  pack_x  <<<dim3(66,32,4), 256, 0, stream>>>(x, xpadT);
  pack_w5a<<<dim3(8,512,9), 256, 0, stream>>>(w5a, W5ab);
  pack_w51<<<dim3(2,512,9), 256, 0, stream>>>(w51, W51b);

  // conv5a: f1 = relu(bn1(conv3x3(x)))
  mfma_gemm<0><<<480, 512, 0, stream>>>(W5ab, xpadT, sc1, sh1,
                                        nullptr, nullptr, f1, nullptr);

  gemm1x1<false,false,false><<<dim3(1,57,4), 256, 0, stream>>>(f1, wq, bq, qb, nullptr, 64, 512, HW);
  gemm1x1<false,false,false><<<dim3(1,57,4), 256, 0, stream>>>(f1, wk, bk, kb, nullptr, 64, 512, HW);
  gemm1x1<false,false,true ><<<dim3(8,57,4), 256, 0, stream>>>(f1, wv, bv, nullptr, vb, 512, 512, SIMS);

  for(int b=0;b<4;b++){
    energy_sim<<<dim3(57,57), 256, 0, stream>>>(qb + (size_t)b*64*HW,
                                                kb + (size_t)b*64*HW,
                                                dep + (size_t)b*HW, lamb1, sim);
    softmax_attn<<<HW, 256, 0, stream>>>(sim, attn + (size_t)b*AROWS*SIMS);
  }

  // PV: sapadT = pad(gamma*out + f1)
  mfma_gemm<2><<<464, 512, 0, stream>>>(vb, attn, nullptr, nullptr,
                                        f1, gamma, nullptr, sapadT);

  // conv51: sc = relu(bn2(conv3x3(sa)))
  mfma_gemm<1><<<480, 512, 0, stream>>>(W51b, sapadT, sc2, sh2,
                                        nullptr, nullptr, nullptr, scb);

  // conv6: logits
  gemm1x1<true,true,false><<<dim3(1,57,4), 256, 0, stream>>>(scb, w6, b6, out, nullptr, 59, 512, HW);
}

// Round 4
// 2642.155 us; speedup vs baseline: 1.2269x; 1.2269x over previous
//
#include <hip/hip_runtime.h>
#include <math.h>

typedef unsigned short u16;
typedef short s16x8 __attribute__((ext_vector_type(8)));
typedef float f32x4 __attribute__((ext_vector_type(4)));

#define HW 3600
#define WID 60
#define SIMS 3616      // padded K/N stride for attention (113*32)
#define AROWS 3712     // attn rows padded to 29*128
#define SP 4216        // 62*68 padded spatial
#define PCIN 2048

__device__ __forceinline__ u16 f2bf(float f){
  unsigned u = __float_as_uint(f);
  unsigned r = (u + 0x7fffu + ((u>>16)&1u)) >> 16;
  return (u16)r;
}
__device__ __forceinline__ float bf2f(u16 b){ return __uint_as_float(((unsigned)b)<<16); }

__device__ __forceinline__ void gl2lds16(const void* g, void* l){
  __builtin_amdgcn_global_load_lds((const __attribute__((address_space(1))) unsigned*)g,
                                   (__attribute__((address_space(3))) unsigned*)l, 16, 0, 0);
}

__device__ __forceinline__ float4 ldg4(const float* __restrict__ p){
  return *reinterpret_cast<const float4*>(p);
}

// ---------------- BN folding ----------------
__global__ void bn_prep(const float* __restrict__ w1, const float* __restrict__ b1,
                        const float* __restrict__ m1, const float* __restrict__ v1,
                        const float* __restrict__ w2, const float* __restrict__ b2,
                        const float* __restrict__ m2, const float* __restrict__ v2,
                        float* __restrict__ sc1, float* __restrict__ sh1,
                        float* __restrict__ sc2, float* __restrict__ sh2){
  int i = threadIdx.x;
  if(i < 512){
    float s1 = w1[i] / sqrtf(v1[i] + 1e-5f);
    sc1[i] = s1; sh1[i] = b1[i] - m1[i]*s1;
    float s2 = w2[i] / sqrtf(v2[i] + 1e-5f);
    sc2[i] = s2; sh2[i] = b2[i] - m2[i]*s2;
  }
}

// ---------------- pack x -> xpadT[plane][b][sp][ci] bf16 split ----------------
__global__ __launch_bounds__(256) void pack_x(const float* __restrict__ x, u16* __restrict__ xpadT){
  __shared__ float tile[64][65];
  const int b = blockIdx.z, sp0 = blockIdx.x*64, ci0 = blockIdx.y*64;
  const int t = threadIdx.x, tc = t & 63, tr = t >> 6;
  const float* xb = x + ((size_t)b*PCIN + ci0)*HW;
  #pragma unroll
  for(int l=0;l<16;l++){
    int ci = tr + l*4;
    int sp = sp0 + tc;
    float v = 0.f;
    if(sp < SP){
      int j = sp / 68, c = sp - j*68;
      int jj = j-1, cc = c-1;
      if((unsigned)jj < 60u && (unsigned)cc < 60u) v = xb[(size_t)ci*HW + jj*60 + cc];
    }
    tile[ci][tc] = v;
  }
  __syncthreads();
  const size_t PL = (size_t)4*SP*PCIN;
  u16* outb = xpadT + (size_t)b*SP*PCIN;
  #pragma unroll
  for(int l=0;l<16;l++){
    int spr = tr + l*4;
    int sp = sp0 + spr;
    if(sp < SP){
      float v = tile[tc][spr];
      u16 hh = f2bf(v);
      u16 ll = f2bf(v - bf2f(hh));
      size_t o = (size_t)sp*PCIN + ci0 + tc;
      outb[o] = hh;
      outb[o + PL] = ll;
    }
  }
}

// ---------------- pack w5a -> [rs][512][6144] (wh | wl | wh) ----------------
__global__ __launch_bounds__(256) void pack_w5a(const float* __restrict__ w, u16* __restrict__ out){
  const int ci = blockIdx.x*256 + threadIdx.x;   // 0..2047
  const int m  = blockIdx.y;
  const int rs = blockIdx.z;
  float v = w[((size_t)m*PCIN + ci)*9 + rs];
  u16 hh = f2bf(v);
  u16 ll = f2bf(v - bf2f(hh));
  size_t base = ((size_t)rs*512 + m)*6144;
  out[base + ci]        = hh;
  out[base + 2048 + ci] = ll;
  out[base + 4096 + ci] = hh;
}

// ---------------- pack w51 -> [rs][512][512] bf16 ----------------
__global__ __launch_bounds__(256) void pack_w51(const float* __restrict__ w, u16* __restrict__ out){
  const int ci = blockIdx.x*256 + threadIdx.x;   // 0..511
  const int m  = blockIdx.y;
  const int rs = blockIdx.z;
  float v = w[((size_t)m*512 + ci)*9 + rs];
  out[((size_t)rs*512 + m)*512 + ci] = f2bf(v);
}

// ---------------- MFMA GEMM (128x128 tile, BK=32, 4 waves 64x64, 3-buf async) ---
// Staging lane-map: thread t loads row ((t>>6)*16 + (t&15)) [+64 for 2nd instr],
// 16B chunk ((t>>4)&3)  -> 4 consecutive lanes cover one row's 64B (16 lines/instr).
// LDS layout (per 8KB region): byte = (row>>4)*1024 + chunk*256 + (row&15)*16.
// MODE 0: conv5a  A=W5a[rs][512][6144], B=xpadT (2 planes), out f1 f32 (BN1+ReLU)
// MODE 1: conv51  A=W51[rs][512][512],  B=sapadT,           out sc bf16 (BN2+ReLU)
// MODE 2: PV      A=v bf16 [512][SIMS], B=attn bf16,        out sapadT (gamma*acc+f1)
template<int MODE>
__global__ __launch_bounds__(256) void mfma_gemm(
    const u16* __restrict__ A, const u16* __restrict__ B,
    const float* __restrict__ scale, const float* __restrict__ shift,
    const float* __restrict__ f1, const float* __restrict__ gamma,
    float* __restrict__ outF, u16* __restrict__ outH)
{
  constexpr int CIC = (MODE==0)? 2048 : 512;
  constexpr int KRS = (MODE==0)? 6144 : 512;
  constexpr int KPR = KRS/32;
  constexpr int NSTEP = (MODE==2)? (SIMS/32) : (9*KPR);
  constexpr int NB  = (MODE==2)? 29 : 30;
  constexpr int GCHUNK = (16*NB) >> 3;     // grid = 4mt*4b*NB, %8==0

  __shared__ __align__(16) u16 lds[3*8192];   // 3 bufs x (A 8KB + B 8KB)

  const int t  = threadIdx.x;

  // bijective XCD-chunked, m-major decomposition
  const int wg = blockIdx.x;
  const int wgid = (wg & 7)*GCHUNK + (wg >> 3);
  const int mt = wgid / (4*NB);
  const int nt = wgid - mt*(4*NB);
  const int m0 = mt << 7;
  const int b  = nt / NB;
  const int nb = nt - b*NB;

  // staging lane permutation
  const int rowA = ((t>>6)<<4) + (t&15);   // 0..63
  const int chnk = (t>>4)&3;

  const u16* Ap[2]; const u16* Bp[2];
  #pragma unroll
  for(int p=0;p<2;p++){
    int r = rowA + p*64;
    if constexpr(MODE==2) Ap[p] = A + (size_t)b*512*SIMS + (size_t)(m0+r)*SIMS + chnk*8;
    else                  Ap[p] = A + (size_t)(m0+r)*KRS + chnk*8;
    if constexpr(MODE==2){
      Bp[p] = B + (size_t)b*AROWS*SIMS + (size_t)(nb*128 + r)*SIMS + chnk*8;
    } else {
      int spb = (nb*2 + p)*68 + rowA;
      Bp[p] = B + (size_t)b*SP*CIC + (size_t)spb*CIC + chnk*8;
    }
  }
  const size_t PL = (size_t)4*SP*PCIN;

  f32x4 acc[4][4];
  #pragma unroll
  for(int i=0;i<4;i++)
    #pragma unroll
    for(int j=0;j<4;j++) acc[i][j] = (f32x4){0.f,0.f,0.f,0.f};

  const int lane = t & 63;
  const int wv = t >> 6;               // 0..3
  const int wm = (wv >> 1) << 6;       // {0,64}
  const int wn = (wv & 1) << 6;        // {0,64}
  const int fr = lane & 15, fq = lane >> 4;
  const char* ldsc = (const char*)lds;
  const int abase = (wm >> 4)*1024 + fq*256 + fr*16;          // A region [0,8192)
  const int bbase = 8192 + (wn >> 4)*1024 + fq*256 + fr*16;   // B region

  auto stage = [&](int st, int q){
    int rs = 0, k0;
    if constexpr(MODE==2){ k0 = st << 5; }
    else { rs = st / KPR; k0 = (st - rs*KPR) << 5; }
    size_t aoffg; size_t boffg;
    int plane = 0, ci0 = 0, rsh = 0;
    if constexpr(MODE==2){ aoffg = k0; boffg = k0; }
    else {
      aoffg = (size_t)rs*512*KRS + k0;
      int r3 = rs/3, s3 = rs - r3*3;
      plane = (MODE==0)? (k0 >> 12) : 0;
      ci0 = k0 & (CIC-1);
      boffg = (size_t)plane*PL + (size_t)(r3*68 + s3)*CIC + ci0;
    }
    u16* lb = &lds[q*8192];
    #pragma unroll
    for(int p=0;p<2;p++){
      gl2lds16(Ap[p] + aoffg, lb + p*2048 + t*8);
      gl2lds16(Bp[p] + boffg, lb + 4096 + p*2048 + t*8);
    }
  };

  auto compute = [&](int q){
    const char* base = ldsc + q*16384;
    s16x8 af[4], bg[4];
    #pragma unroll
    for(int i=0;i<4;i++) af[i] = *(const s16x8*)(base + abase + i*1024);
    #pragma unroll
    for(int j=0;j<4;j++) bg[j] = *(const s16x8*)(base + bbase + j*1024);
    __builtin_amdgcn_s_setprio(1);
    #pragma unroll
    for(int i=0;i<4;i++)
      #pragma unroll
      for(int j=0;j<4;j++)
        acc[i][j] = __builtin_amdgcn_mfma_f32_16x16x32_bf16(af[i], bg[j], acc[i][j], 0,0,0);
    __builtin_amdgcn_s_setprio(0);
  };

  // prologue: 2 tiles in flight, 4 loads/thread each
  stage(0, 0);
  stage(1, 1);
  int cur = 0;
  for(int st = 0; st < NSTEP-2; ++st){
    int q2 = cur + 2; if(q2 >= 3) q2 -= 3;
    stage(st+2, q2);
    asm volatile("s_waitcnt vmcnt(8)" ::: "memory");
    __builtin_amdgcn_s_barrier();
    asm volatile("" ::: "memory");
    compute(cur);
    asm volatile("" ::: "memory");
    __builtin_amdgcn_s_barrier();
    asm volatile("" ::: "memory");
    cur = (cur+1 == 3)? 0 : cur+1;
  }
  asm volatile("s_waitcnt vmcnt(4)" ::: "memory");
  __builtin_amdgcn_s_barrier();
  asm volatile("" ::: "memory");
  compute(cur);
  cur = (cur+1 == 3)? 0 : cur+1;
  asm volatile("s_waitcnt vmcnt(0)" ::: "memory");
  __builtin_amdgcn_s_barrier();
  asm volatile("" ::: "memory");
  compute(cur);

  if constexpr(MODE==0 || MODE==1){
    #pragma unroll
    for(int i=0;i<4;i++){
      #pragma unroll
      for(int q=0;q<4;q++){
        int m = m0 + wm + i*16 + fq*4 + q;
        float scl = scale[m], shf = shift[m];
        #pragma unroll
        for(int j=0;j<4;j++){
          int np = nb*128 + wn + j*16 + fr;
          int h = np>>6, w = np&63;
          if(w < 60){
            float v = fmaxf(fmaf(acc[i][j][q], scl, shf), 0.f);
            size_t o = ((size_t)b*512 + m)*HW + h*60 + w;
            if constexpr(MODE==0) outF[o] = v;
            else                  outH[o] = f2bf(v);
          }
        }
      }
    }
  } else {
    float g = gamma[0];
    #pragma unroll
    for(int j=0;j<4;j++){
      int ip = nb*128 + wn + j*16 + fr;
      if(ip < HW){
        int h = ip/60, w = ip - h*60;
        size_t spo = (size_t)b*SP*512 + (size_t)((h+1)*68 + (w+1))*512;
        #pragma unroll
        for(int i=0;i<4;i++){
          #pragma unroll
          for(int q=0;q<4;q++){
            int m = m0 + wm + i*16 + fq*4 + q;
            float v = fmaf(g, acc[i][j][q], f1[((size_t)b*512 + m)*HW + ip]);
            outH[spo + m] = f2bf(v);
          }
        }
      }
    }
  }
}

// ---------------- 1x1 conv GEMM (f32 compute) ----------------
template<bool INBF, bool GM, bool OUTBF>
__global__ __launch_bounds__(256) void gemm1x1(const void* __restrict__ inv,
    const float* __restrict__ w, const float* __restrict__ bias,
    float* __restrict__ outF, u16* __restrict__ outH, int M, int K, int OS)
{
  const int b  = blockIdx.z;
  const int m0 = blockIdx.x * 64;
  const int n0 = blockIdx.y * 64;
  const int t  = threadIdx.x;
  const int tm = t >> 4, tn = t & 15;

  __shared__ __align__(16) float As[16][64];
  __shared__ __align__(16) float Bs[16][64];

  float acc[4][4] = {};

  const int arow = t >> 2, acol = (t & 3) << 2;
  const int bkk  = t & 15, bnl  = (t >> 4) << 2;
  const bool bvalid = (n0 + bnl) < HW;

  for(int k0 = 0; k0 < K; k0 += 16){
    float4 av = make_float4(0.f,0.f,0.f,0.f);
    if(!GM || (m0 + arow) < M)
      av = ldg4(&w[(size_t)(m0 + arow)*K + k0 + acol]);
    As[acol+0][arow] = av.x;
    As[acol+1][arow] = av.y;
    As[acol+2][arow] = av.z;
    As[acol+3][arow] = av.w;

    float4 bv = make_float4(0.f,0.f,0.f,0.f);
    if(bvalid){
      if constexpr(INBF){
        const u16* inb = (const u16*)inv + (size_t)b*K*HW;
        const u16* p = &inb[(size_t)(k0 + bkk)*HW + n0 + bnl];
        bv.x = bf2f(p[0]); bv.y = bf2f(p[1]); bv.z = bf2f(p[2]); bv.w = bf2f(p[3]);
      } else {
        const float* inb = (const float*)inv + (size_t)b*K*HW;
        bv = ldg4(&inb[(size_t)(k0 + bkk)*HW + n0 + bnl]);
      }
    }
    *reinterpret_cast<float4*>(&Bs[bkk][bnl]) = bv;

    __syncthreads();
    #pragma unroll
    for(int kk=0;kk<16;kk++){
      float4 a  = *reinterpret_cast<const float4*>(&As[kk][tm<<2]);
      float4 bb = *reinterpret_cast<const float4*>(&Bs[kk][tn<<2]);
      float ar[4] = {a.x,a.y,a.z,a.w};
      float br[4] = {bb.x,bb.y,bb.z,bb.w};
      #pragma unroll
      for(int ii=0;ii<4;ii++)
        #pragma unroll
        for(int jj=0;jj<4;jj++)
          acc[ii][jj] = fmaf(ar[ii], br[jj], acc[ii][jj]);
    }
    __syncthreads();
  }

  int n = n0 + (tn<<2);
  if(n < OS){
    #pragma unroll
    for(int ii=0;ii<4;ii++){
      int m = m0 + (tm<<2) + ii;
      if(!GM || m < M){
        float bi = bias[m];
        #pragma unroll
        for(int jj=0;jj<4;jj++){
          int nn = n + jj;
          float val = (nn < HW) ? (acc[ii][jj] + bi) : 0.f;
          if constexpr(OUTBF) outH[((size_t)b*M + m)*OS + nn] = f2bf(val);
          else                outF[((size_t)b*M + m)*OS + nn] = val;
        }
      }
    }
  }
}

// ---------------- energy + depth penalty (f32) ----------------
__global__ __launch_bounds__(256) void energy_sim(
    const float* __restrict__ q, const float* __restrict__ kptr,
    const float* __restrict__ dep, const float* __restrict__ lamb1,
    float* __restrict__ sim)
{
  const int i0 = blockIdx.y * 64;
  const int j0 = blockIdx.x * 64;
  const int t  = threadIdx.x;
  const int tm = t >> 4, tn = t & 15;

  __shared__ __align__(16) float Qs[64][64];
  __shared__ __align__(16) float Ks[64][64];

  {
    const int cc = t >> 4;
    const int il = (t & 15) << 2;
    #pragma unroll
    for(int it=0; it<4; it++){
      int c = cc + it*16;
      float4 qv = make_float4(0.f,0.f,0.f,0.f);
      float4 kv = make_float4(0.f,0.f,0.f,0.f);
      if(i0 + il < HW) qv = ldg4(&q[(size_t)c*HW + i0 + il]);
      if(j0 + il < HW) kv = ldg4(&kptr[(size_t)c*HW + j0 + il]);
      *reinterpret_cast<float4*>(&Qs[c][il]) = qv;
      *reinterpret_cast<float4*>(&Ks[c][il]) = kv;
    }
  }
  __syncthreads();

  float acc[4][4] = {};
  #pragma unroll 4
  for(int c=0;c<64;c++){
    float4 a  = *reinterpret_cast<const float4*>(&Qs[c][tm<<2]);
    float4 bv = *reinterpret_cast<const float4*>(&Ks[c][tn<<2]);
    float ar[4] = {a.x,a.y,a.z,a.w};
    float br[4] = {bv.x,bv.y,bv.z,bv.w};
    #pragma unroll
    for(int ii=0;ii<4;ii++)
      #pragma unroll
      for(int jj=0;jj<4;jj++)
        acc[ii][jj] = fmaf(ar[ii], br[jj], acc[ii][jj]);
  }

  float lam = lamb1[0];
  float di[4], dj[4];
  #pragma unroll
  for(int ii=0;ii<4;ii++){ int i = i0+(tm<<2)+ii; di[ii] = (i<HW)? dep[i] : 0.f; }
  #pragma unroll
  for(int jj=0;jj<4;jj++){ int j = j0+(tn<<2)+jj; dj[jj] = (j<HW)? dep[j] : 0.f; }

  int j = j0 + (tn<<2);
  if(j < HW){
    #pragma unroll
    for(int ii=0;ii<4;ii++){
      int i = i0 + (tm<<2) + ii;
      if(i < HW){
        float4 o;
        float d0 = di[ii]-dj[0]; o.x = acc[ii][0] - lam*d0*d0;
        float d1 = di[ii]-dj[1]; o.y = acc[ii][1] - lam*d1*d1;
        float d2 = di[ii]-dj[2]; o.z = acc[ii][2] - lam*d2*d2;
        float d3 = di[ii]-dj[3]; o.w = acc[ii][3] - lam*d3*d3;
        *reinterpret_cast<float4*>(&sim[(size_t)i*SIMS + j]) = o;
      }
    }
  }
}

// ---------------- row softmax -> bf16 attn (2-pass, online max/sum) ----------------
__global__ __launch_bounds__(256) void softmax_attn(const float* __restrict__ sim,
                                                    u16* __restrict__ attn){
  __shared__ float redM[4], redS[4];
  const int row = blockIdx.x;
  const float* p = sim + (size_t)row*SIMS;
  u16*   a = attn + (size_t)row*SIMS;
  const int wid = threadIdx.x >> 6, lane = threadIdx.x & 63;

  float m = -3.4e38f, s = 0.f;
  for(int j=threadIdx.x; j<HW; j+=256){
    float v = p[j];
    float mo = m;
    m = fmaxf(m, v);
    s = s*__expf(mo - m) + __expf(v - m);
  }
  #pragma unroll
  for(int o=32;o>0;o>>=1){
    float m2 = __shfl_xor(m, o, 64);
    float s2 = __shfl_xor(s, o, 64);
    float mn = fmaxf(m, m2);
    s = s*__expf(m - mn) + s2*__expf(m2 - mn);
    m = mn;
  }
  if(lane==0){ redM[wid] = m; redS[wid] = s; }
  __syncthreads();
  float M = fmaxf(fmaxf(redM[0],redM[1]), fmaxf(redM[2],redM[3]));
  float S = redS[0]*__expf(redM[0]-M) + redS[1]*__expf(redM[1]-M)
          + redS[2]*__expf(redM[2]-M) + redS[3]*__expf(redM[3]-M);
  float inv = 1.0f / S;
  for(int j=threadIdx.x; j<HW; j+=256) a[j] = f2bf(__expf(p[j]-M) * inv);
  if(threadIdx.x < SIMS-HW) a[HW + threadIdx.x] = 0;
}

extern "C" void kernel_launch(void* const* d_in, const int* in_sizes, int n_in,
                              void* d_out, int out_size, void* d_ws, size_t ws_size,
                              hipStream_t stream)
{
  const float* x    = (const float*)d_in[0];
  const float* dep  = (const float*)d_in[1];
  const float* w5a  = (const float*)d_in[2];
  const float* bn1w = (const float*)d_in[3];
  const float* bn1b = (const float*)d_in[4];
  const float* bn1m = (const float*)d_in[5];
  const float* bn1v = (const float*)d_in[6];
  const float* wq   = (const float*)d_in[7];
  const float* bq   = (const float*)d_in[8];
  const float* wk   = (const float*)d_in[9];
  const float* bk   = (const float*)d_in[10];
  const float* wv   = (const float*)d_in[11];
  const float* bv   = (const float*)d_in[12];
  const float* gamma= (const float*)d_in[13];
  const float* lamb1= (const float*)d_in[14];
  const float* w51  = (const float*)d_in[15];
  const float* bn2w = (const float*)d_in[16];
  const float* bn2b = (const float*)d_in[17];
  const float* bn2m = (const float*)d_in[18];
  const float* bn2v = (const float*)d_in[19];
  const float* w6   = (const float*)d_in[20];
  const float* b6   = (const float*)d_in[21];
  float* out = (float*)d_out;

  char* cur = (char*)d_ws;
  auto alloc = [&](size_t bytes)->char*{ char* p = cur; cur += (bytes + 255) & ~(size_t)255; return p; };

  float* sc1 = (float*)alloc(512*4);
  float* sh1 = (float*)alloc(512*4);
  float* sc2 = (float*)alloc(512*4);
  float* sh2 = (float*)alloc(512*4);
  u16* xpadT = (u16*)alloc((size_t)2*4*SP*PCIN*2);
  u16* W5ab  = (u16*)alloc((size_t)9*512*6144*2);
  u16* W51b  = (u16*)alloc((size_t)9*512*512*2);
  float* f1  = (float*)alloc((size_t)4*512*HW*4);
  float* qb  = (float*)alloc((size_t)4*64*HW*4);
  float* kb  = (float*)alloc((size_t)4*64*HW*4);
  u16* vb    = (u16*)alloc((size_t)4*512*SIMS*2);
  float* sim = (float*)alloc((size_t)HW*SIMS*4);
  u16* attn  = (u16*)alloc((size_t)4*AROWS*SIMS*2);
  u16* sapadT= (u16*)alloc((size_t)4*SP*512*2);
  u16* scb   = (u16*)alloc((size_t)4*512*HW*2);

  bn_prep<<<1, 512, 0, stream>>>(bn1w,bn1b,bn1m,bn1v, bn2w,bn2b,bn2m,bn2v,
                                 sc1,sh1,sc2,sh2);

  hipMemsetAsync(sapadT, 0, (size_t)4*SP*512*2, stream);

  pack_x  <<<dim3(66,32,4), 256, 0, stream>>>(x, xpadT);
  pack_w5a<<<dim3(8,512,9), 256, 0, stream>>>(w5a, W5ab);
  pack_w51<<<dim3(2,512,9), 256, 0, stream>>>(w51, W51b);

  // conv5a: f1 = relu(bn1(conv3x3(x)))
  mfma_gemm<0><<<480, 256, 0, stream>>>(W5ab, xpadT, sc1, sh1,
                                        nullptr, nullptr, f1, nullptr);

  gemm1x1<false,false,false><<<dim3(1,57,4), 256, 0, stream>>>(f1, wq, bq, qb, nullptr, 64, 512, HW);
  gemm1x1<false,false,false><<<dim3(1,57,4), 256, 0, stream>>>(f1, wk, bk, kb, nullptr, 64, 512, HW);
  gemm1x1<false,false,true ><<<dim3(8,57,4), 256, 0, stream>>>(f1, wv, bv, nullptr, vb, 512, 512, SIMS);

  for(int b=0;b<4;b++){
    energy_sim<<<dim3(57,57), 256, 0, stream>>>(qb + (size_t)b*64*HW,
                                                kb + (size_t)b*64*HW,
                                                dep + (size_t)b*HW, lamb1, sim);
    softmax_attn<<<HW, 256, 0, stream>>>(sim, attn + (size_t)b*AROWS*SIMS);
  }

  // PV: sapadT = pad(gamma*out + f1)
  mfma_gemm<2><<<464, 256, 0, stream>>>(vb, attn, nullptr, nullptr,
                                        f1, gamma, nullptr, sapadT);

  // conv51: sc = relu(bn2(conv3x3(sa)))
  mfma_gemm<1><<<480, 256, 0, stream>>>(W51b, sapadT, sc2, sh2,
                                        nullptr, nullptr, nullptr, scb);

  // conv6: logits
  gemm1x1<true,true,false><<<dim3(1,57,4), 256, 0, stream>>>(scb, w6, b6, out, nullptr, 59, 512, HW);
}